// Round 12
// baseline (28.934 us; speedup 1.0000x reference)
//
#include <hip/hip_runtime.h>

#define BB 2
#define SDIM 1024
#define DDIM 128

#define F4GET(v,k) ((k)==0?(v).x:((k)==1?(v).y:((k)==2?(v).z:(v).w)))

typedef _Float16 h2v __attribute__((ext_vector_type(2)));
typedef _Float16 h8v __attribute__((ext_vector_type(8)));

__device__ __forceinline__ h2v habs2(h2v t) {
    unsigned u = __builtin_bit_cast(unsigned, t) & 0x7FFF7FFFu;
    return __builtin_bit_cast(h2v, u);
}

__device__ __forceinline__ h2v hfma2(h2v a, h2v b, h2v c) {
#if __has_builtin(__builtin_elementwise_fma)
    return __builtin_elementwise_fma(a, b, c);   // v_pk_fma_f16
#else
    return a * b + c;
#endif
}

// Row swizzle: rows 8/16 apart land on different bank-quads.
__device__ __forceinline__ int rswz(int row) {
    return (row & 7) ^ ((row >> 3) & 7);
}

// ---------------- Kernel 1: projections + row dot products ----------------
// Grid (256 rowgroups, 2 W1-halves) x 256 thr; thread = (d, khalf).
// Each block: 8 rows of ONE half; k contraction split across khalf, combined
// in LDS. W1 L2 traffic = 512 x 64 KB = 32 MB (was 128 MB). 2 blocks/CU.
__global__ __launch_bounds__(256) void proj_kernel(
    const float* __restrict__ x, const float* __restrict__ W1,
    const float* __restrict__ b1, const float* __restrict__ W2,
    const float* __restrict__ b2,
    ushort* __restrict__ hi16, ushort* __restrict__ hjb16,
    float* __restrict__ si2, float* __restrict__ sj2)
{
    __shared__ float sX[8][DDIM];     // 4 KB x-tile
    __shared__ float sH[8][DDIM];     // 4 KB combine buffer
    __shared__ float sRed[2][8];
    const int tid  = threadIdx.x;
    const int d    = tid & 127;
    const int kh   = tid >> 7;              // k-half: k in [64*kh, 64*kh+64)
    const int half = blockIdx.y;            // 0 -> hi, 1 -> hjb
    const int r0   = blockIdx.x * 8;

    // Stage 8 x-rows (1024 floats = 256 float4, one per thread).
    reinterpret_cast<float4*>(&sX[0][0])[tid] =
        reinterpret_cast<const float4*>(x + (size_t)r0 * DDIM)[tid];
    __syncthreads();

    // W1 column d, rows [half*128 + kh*64 ...).
    const float* Wp = W1 + ((size_t)half * DDIM + kh * 64) * DDIM + d;

    float acc[8];
    #pragma unroll
    for (int r = 0; r < 8; ++r) acc[r] = 0.f;

    #pragma unroll 4
    for (int kc = 0; kc < 16; ++kc) {       // 16 chunks of 4 k
        float4 xv[8];
        #pragma unroll
        for (int r = 0; r < 8; ++r)
            xv[r] = *reinterpret_cast<const float4*>(&sX[r][kh * 64 + kc * 4]);
        #pragma unroll
        for (int kk = 0; kk < 4; ++kk) {
            const float w = Wp[(size_t)(kc * 4 + kk) * DDIM];
            #pragma unroll
            for (int r = 0; r < 8; ++r)
                acc[r] = fmaf(F4GET(xv[r], kk), w, acc[r]);
        }
    }

    // Combine k-halves: kh=1 publishes, kh=0 finalizes.
    if (kh == 1) {
        #pragma unroll
        for (int r = 0; r < 8; ++r) sH[r][d] = acc[r];
    }
    __syncthreads();
    if (kh == 0) {
        const float bv = half ? b1[d] : 0.f;
        const float wv = W2[d];
        ushort* hout = half ? hjb16 : hi16;
        const int lane = tid & 63;
        const int wave = tid >> 6;          // 0 or 1
        #pragma unroll
        for (int r = 0; r < 8; ++r) {
            float h = acc[r] + sH[r][d] + bv;
            _Float16 hv = (_Float16)h;
            hout[(size_t)(r0 + r) * DDIM + d] = __builtin_bit_cast(ushort, hv);
            float v = h * wv;
            #pragma unroll
            for (int off = 32; off >= 1; off >>= 1)
                v += __shfl_xor(v, off, 64);
            if (lane == 0) sRed[wave][r] = v;
        }
    }
    __syncthreads();
    if (tid < 8) {
        float s = 0.5f * (sRed[0][tid] + sRed[1][tid]);
        if (half == 0) si2[r0 + tid] = s;
        else           sj2[r0 + tid] = s + b2[0];
    }
}

// ---------------- Kernel 2: pairwise edge logits ----------------
// BYTE-IDENTICAL to R10 edge_kernel_b (measured contribution: 15.6 us).
// out[b,i,j] = si2[b,i] + sj2[b,j] + sum_d |hi[b,i,d]+hjb[b,j,d]| * 0.5*w2[d]
__global__ __launch_bounds__(256) void edge_kernel(
    const ushort* __restrict__ hi16, const ushort* __restrict__ hjb16,
    const float* __restrict__ si2, const float* __restrict__ sj2,
    const float* __restrict__ W2, float* __restrict__ out)
{
    __shared__ ushort sHi[64 * DDIM];
    __shared__ ushort sHj[64 * DDIM];
    __shared__ ushort sWh[DDIM];
    __shared__ float  sSi[64];
    __shared__ float  sSj[64];

    const int b   = blockIdx.z;
    const int i0  = blockIdx.y * 64;
    const int j0  = blockIdx.x * 64;
    const int tid = threadIdx.x;

    {
        const h8v* srcI = reinterpret_cast<const h8v*>(hi16  + ((size_t)b * SDIM + i0) * DDIM);
        const h8v* srcJ = reinterpret_cast<const h8v*>(hjb16 + ((size_t)b * SDIM + j0) * DDIM);
        h8v* dI = reinterpret_cast<h8v*>(sHi);
        h8v* dJ = reinterpret_cast<h8v*>(sHj);
        #pragma unroll
        for (int p = 0; p < 4; ++p) {
            int idx = p * 256 + tid;
            int row = idx >> 4, ch = idx & 15;
            int cs  = ch ^ rswz(row);
            dI[row * 16 + cs] = srcI[idx];
            dJ[row * 16 + cs] = srcJ[idx];
        }
    }
    if (tid < DDIM) {
        _Float16 wv = (_Float16)(0.5f * W2[tid]);
        sWh[tid] = __builtin_bit_cast(ushort, wv);
    } else if (tid < DDIM + 64) {
        sSi[tid - DDIM] = si2[b * SDIM + i0 + (tid - DDIM)];
    } else {
        sSj[tid - DDIM - 64] = sj2[b * SDIM + j0 + (tid - DDIM - 64)];
    }
    __syncthreads();

    const int tx = tid & 15;
    const int ty = tid >> 4;
    const int ri = ty * 4;
    const int cj = tx * 4;

    int swzA[4], swzB[4];
    #pragma unroll
    for (int r = 0; r < 4; ++r) swzA[r] = rswz(ri + r);
    #pragma unroll
    for (int c = 0; c < 4; ++c) swzB[c] = rswz(cj + c);

    h2v accP[4][4], accQ[4][4];
    #pragma unroll
    for (int r = 0; r < 4; ++r)
        #pragma unroll
        for (int c = 0; c < 4; ++c) {
            accP[r][c] = (h2v)(_Float16)0;
            accQ[r][c] = (h2v)(_Float16)0;
        }

    const h8v* sAi = reinterpret_cast<const h8v*>(sHi);
    const h8v* sBj = reinterpret_cast<const h8v*>(sHj);
    const h8v* sWv = reinterpret_cast<const h8v*>(sWh);

    #pragma unroll 2
    for (int ch = 0; ch < 16; ++ch) {
        h8v A[4], Bv[4];
        #pragma unroll
        for (int r = 0; r < 4; ++r)
            A[r] = sAi[(ri + r) * 16 + (ch ^ swzA[r])];
        #pragma unroll
        for (int c = 0; c < 4; ++c)
            Bv[c] = sBj[(cj + c) * 16 + (ch ^ swzB[c])];
        const h8v Wv = sWv[ch];
        const h2v* wp = reinterpret_cast<const h2v*>(&Wv);

        #pragma unroll
        for (int r = 0; r < 4; ++r) {
            const h2v* ap = reinterpret_cast<const h2v*>(&A[r]);
            #pragma unroll
            for (int c = 0; c < 4; ++c) {
                const h2v* bp = reinterpret_cast<const h2v*>(&Bv[c]);
                h2v t0 = ap[0] + bp[0];            // v_pk_add_f16
                h2v t1 = ap[1] + bp[1];
                h2v t2 = ap[2] + bp[2];
                h2v t3 = ap[3] + bp[3];
                accP[r][c] = hfma2(habs2(t0), wp[0], accP[r][c]);  // v_pk_fma_f16
                accP[r][c] = hfma2(habs2(t1), wp[1], accP[r][c]);
                accQ[r][c] = hfma2(habs2(t2), wp[2], accQ[r][c]);
                accQ[r][c] = hfma2(habs2(t3), wp[3], accQ[r][c]);
            }
        }
    }

    #pragma unroll
    for (int r = 0; r < 4; ++r) {
        const float sv = sSi[ri + r];
        float4 o;
        o.x = ((float)accP[r][0].x + (float)accP[r][0].y)
            + ((float)accQ[r][0].x + (float)accQ[r][0].y) + sv + sSj[cj + 0];
        o.y = ((float)accP[r][1].x + (float)accP[r][1].y)
            + ((float)accQ[r][1].x + (float)accQ[r][1].y) + sv + sSj[cj + 1];
        o.z = ((float)accP[r][2].x + (float)accP[r][2].y)
            + ((float)accQ[r][2].x + (float)accQ[r][2].y) + sv + sSj[cj + 2];
        o.w = ((float)accP[r][3].x + (float)accP[r][3].y)
            + ((float)accQ[r][3].x + (float)accQ[r][3].y) + sv + sSj[cj + 3];
        size_t base = (size_t)b * SDIM * SDIM + (size_t)(i0 + ri + r) * SDIM + j0 + cj;
        *reinterpret_cast<float4*>(out + base) = o;
    }
}

extern "C" void kernel_launch(void* const* d_in, const int* in_sizes, int n_in,
                              void* d_out, int out_size, void* d_ws, size_t ws_size,
                              hipStream_t stream) {
    const float* x  = (const float*)d_in[0];
    const float* W1 = (const float*)d_in[1];
    const float* b1 = (const float*)d_in[2];
    const float* W2 = (const float*)d_in[3];
    const float* b2 = (const float*)d_in[4];
    float* out = (float*)d_out;

    char* ws = (char*)d_ws;
    ushort* hi16  = (ushort*)ws;                                   // B*S*D f16
    ushort* hjb16 = hi16 + (size_t)BB * SDIM * DDIM;               // B*S*D f16
    float*  si2   = (float*)(hjb16 + (size_t)BB * SDIM * DDIM);    // B*S f32
    float*  sj2   = si2 + (size_t)BB * SDIM;                       // B*S f32

    proj_kernel<<<dim3(BB * SDIM / 8, 2), 256, 0, stream>>>(x, W1, b1, W2, b2, hi16, hjb16, si2, sj2);
    edge_kernel<<<dim3(SDIM / 64, SDIM / 64, BB), 256, 0, stream>>>(hi16, hjb16, si2, sj2, W2, out);
}